// Round 11
// baseline (766.545 us; speedup 1.0000x reference)
//
#include <hip/hip_runtime.h>
#include <hip/hip_bf16.h>
#include <math.h>

#define N 8192
#define F 133
#define FP 136
#define H 256
#define MF 200
#define RH 512
#define MAXDEG 128

typedef unsigned short bfu;

static __device__ __forceinline__ bfu f2bf(float f) {
    unsigned u = __builtin_bit_cast(unsigned, f);
    u = (u + 0x7fff + ((u >> 16) & 1)) >> 16;   // RNE, finite inputs
    return (bfu)u;
}
static __device__ __forceinline__ float bf2f(bfu b) {
    unsigned u = (unsigned)b << 16;
    return __builtin_bit_cast(float, u);
}

// ==== k_front: h0+scores0 (blocks 0..255) | A->bitmask stream (256..2303) ====
// Scan phase 1 is BRANCHLESS: 8 independent 1KB loads per wave-iter, per-lane
// mask build with cmp+select, coalesced uint32 stores. No atomics, no ballot.
__global__ __launch_bounds__(256) void k_front(
    const float4* __restrict__ A4, unsigned* __restrict__ bmask,
    const float* __restrict__ X, const float* __restrict__ Win,
    const float* __restrict__ bin, const float* __restrict__ Watt,
    bfu* __restrict__ hb, float* __restrict__ snei, float* __restrict__ sself) {
    const int t = threadIdx.x;
    const int b = blockIdx.x;
    if (b >= 256) {
        const int wave = t >> 6;
        const int lane = t & 63;
        const int row = (b - 256) * 4 + wave;
        const float4* rowp = A4 + (size_t)row * (N / 4);
        unsigned* bm = bmask + row * 256;
#pragma unroll 1
        for (int c = 0; c < 4; ++c) {
            float4 v[8];
#pragma unroll
            for (int j = 0; j < 8; ++j) v[j] = rowp[c * 512 + j * 64 + lane];
            unsigned m = 0;
#pragma unroll
            for (int j = 0; j < 8; ++j) {
                const float* vp = &v[j].x;
#pragma unroll
                for (int q = 0; q < 4; ++q)
                    m |= (vp[q] != 0.0f) ? (1u << (j * 4 + q)) : 0u;
            }
            bm[c * 64 + lane] = m;
        }
        return;
    }
    // ---------------- h0 = X @ W_in + b_in -> bf16, + scores of h0 ----------------
    __shared__ float xs[32][FP];
    __shared__ float sredN[32][4];
    __shared__ float sredS[32][4];
    const int row0 = b * 32;
    for (int i = t; i < 32 * F; i += 256) {
        int r = i / F, f = i - r * F;
        xs[r][f] = X[(row0 + r) * F + f];
    }
    __syncthreads();
    float acc[32];
#pragma unroll
    for (int r = 0; r < 32; ++r) acc[r] = 0.f;
    for (int f = 0; f < 132; f += 4) {
        float w0 = Win[(f + 0) * H + t];
        float w1 = Win[(f + 1) * H + t];
        float w2 = Win[(f + 2) * H + t];
        float w3 = Win[(f + 3) * H + t];
#pragma unroll
        for (int r = 0; r < 32; ++r) {
            float4 xv = *reinterpret_cast<const float4*>(&xs[r][f]);
            acc[r] = fmaf(xv.x, w0, acc[r]);
            acc[r] = fmaf(xv.y, w1, acc[r]);
            acc[r] = fmaf(xv.z, w2, acc[r]);
            acc[r] = fmaf(xv.w, w3, acc[r]);
        }
    }
    {
        float w0 = Win[132 * H + t];
#pragma unroll
        for (int r = 0; r < 32; ++r) acc[r] = fmaf(xs[r][132], w0, acc[r]);
    }
    const float bb = bin[t];
    const float wan = Watt[t];
    const float was = Watt[H + t];
    const int wv = t >> 6, ln = t & 63;
#pragma unroll
    for (int r = 0; r < 32; ++r) {
        float v = acc[r] + bb;
        hb[(row0 + r) * H + t] = f2bf(v);
        float pn = v * wan;
        float ps = v * was;
        for (int off = 32; off > 0; off >>= 1) {
            pn += __shfl_down(pn, off);
            ps += __shfl_down(ps, off);
        }
        if (ln == 0) { sredN[r][wv] = pn; sredS[r][wv] = ps; }
    }
    __syncthreads();
    if (t < 32)
        snei[row0 + t] = (sredN[t][0] + sredN[t][1]) + (sredN[t][2] + sredN[t][3]);
    else if (t < 64) {
        int r = t - 32;
        sself[row0 + r] = (sredS[r][0] + sredS[r][1]) + (sredS[r][2] + sredS[r][3]);
    }
}

// ==== k_extract: bitmask -> (cnt, colidx). Wave per row, shfl prefix scan. ====
__global__ __launch_bounds__(256) void k_extract(
    const unsigned* __restrict__ bmask, int* __restrict__ cnt,
    int* __restrict__ colidx) {
    const int wave = threadIdx.x >> 6;
    const int lane = threadIdx.x & 63;
    const int row = blockIdx.x * 4 + wave;
    unsigned w[4];
#pragma unroll
    for (int c = 0; c < 4; ++c) w[c] = bmask[row * 256 + c * 64 + lane];
    int tl = __popc(w[0]) + __popc(w[1]) + __popc(w[2]) + __popc(w[3]);
    // inclusive prefix over 64 lanes
    int inc = tl;
#pragma unroll
    for (int d = 1; d < 64; d <<= 1) {
        int nb = __shfl_up(inc, d);
        if (lane >= d) inc += nb;
    }
    const int off = inc - tl;
    if (lane == 63) cnt[row] = inc < MAXDEG ? inc : MAXDEG;
    int o = off;
    int* rowout = colidx + row * MAXDEG;
#pragma unroll
    for (int c = 0; c < 4; ++c) {
        unsigned m = w[c];
        const int base = c * 2048 + lane * 4;
        while (m) {
            int p = __ffs(m) - 1;
            m &= m - 1;
            if (o < MAXDEG) rowout[o] = base + ((p >> 2) << 8) + (p & 3);
            ++o;
        }
    }
}

// ============ k_agg: gather h (bf16) -> hg (fp32); zero next score bufs ============
__global__ __launch_bounds__(256, 4) void k_agg(
    const bfu* __restrict__ hb, float* __restrict__ hg,
    const int* __restrict__ cnt, const int* __restrict__ colidx,
    const float* __restrict__ snei_in, const float* __restrict__ sself_in,
    const float* __restrict__ b_att,
    float* __restrict__ zn, float* __restrict__ zs) {
    __shared__ float wls[512];
    __shared__ int   jls[512];
    __shared__ float sselfL[4];
    __shared__ int   ncnt[4];
    const int t = threadIdx.x;
    const int w = t >> 6, l = t & 63;
    const int c0 = l << 2;
    const int R0 = blockIdx.x * 4;
    if (blockIdx.x < 64) {   // zero the score buffers the next k_node atomic-adds
        if (t < 128) zn[blockIdx.x * 128 + t] = 0.f;
        else         zs[blockIdx.x * 128 + (t - 128)] = 0.f;
    }
    if (t < 4) { ncnt[t] = cnt[R0 + t]; sselfL[t] = sself_in[R0 + t] + b_att[0]; }
    __syncthreads();
#pragma unroll
    for (int rep = 0; rep < 2; ++rep) {
        int idx = t + rep * 256;
        int r = idx >> 7, k = idx & 127;
        if (k < ncnt[r]) {
            int j = colidx[(R0 + r) * MAXDEG + k];
            jls[idx] = j;
            wls[idx] = 1.f / (1.f + __expf(-(sselfL[r] + snei_in[j])));
        }
    }
    __syncthreads();
    const int n = ncnt[w];
#define GSTEP(u, sx, sy, sz, sw)                                                  \
    { int ju = jls[w * 128 + k + u]; float wv = wls[w * 128 + k + u];             \
      ushort4 hv = *reinterpret_cast<const ushort4*>(&hb[ju * 256 + c0]);         \
      sx = fmaf(wv, bf2f(hv.x), sx); sy = fmaf(wv, bf2f(hv.y), sy);               \
      sz = fmaf(wv, bf2f(hv.z), sz); sw = fmaf(wv, bf2f(hv.w), sw); }
    float x0=0,y0=0,z0=0,w0=0, x1=0,y1=0,z1=0,w1=0;
    float x2=0,y2=0,z2=0,w2=0, x3=0,y3=0,z3=0,w3=0;
    float x4=0,y4=0,z4=0,w4=0, x5=0,y5=0,z5=0,w5=0;
    float x6=0,y6=0,z6=0,w6=0, x7=0,y7=0,z7=0,w7=0;
    int k = 0;
    for (; k + 8 <= n; k += 8) {
        GSTEP(0,x0,y0,z0,w0) GSTEP(1,x1,y1,z1,w1)
        GSTEP(2,x2,y2,z2,w2) GSTEP(3,x3,y3,z3,w3)
        GSTEP(4,x4,y4,z4,w4) GSTEP(5,x5,y5,z5,w5)
        GSTEP(6,x6,y6,z6,w6) GSTEP(7,x7,y7,z7,w7)
    }
    for (; k < n; ++k) { GSTEP(0,x0,y0,z0,w0) }
#undef GSTEP
    float4 st;
    st.x = ((x0+x1)+(x2+x3)) + ((x4+x5)+(x6+x7));
    st.y = ((y0+y1)+(y2+y3)) + ((y4+y5)+(y6+y7));
    st.z = ((z0+z1)+(z2+z3)) + ((z4+z5)+(z6+z7));
    st.w = ((w0+w1)+(w2+w3)) + ((w4+w5)+(w6+w7));
    *reinterpret_cast<float4*>(&hg[(size_t)(R0 + w) * 256 + c0]) = st;
}

// ===== k_node: h_next = relu(hg @ W + b); epilogue: atomic scores | colsum part =====
#define BM 64
#define BN 64
#define BK 32
#define AP 68
template <bool LAST>
__global__ __launch_bounds__(256) void k_node(
    const float* __restrict__ hin, bfu* __restrict__ hout,
    const float* __restrict__ W, const float* __restrict__ b,
    const float* __restrict__ Watt,
    float* __restrict__ snei_out, float* __restrict__ sself_out,
    float* __restrict__ part) {
    __shared__ float As[BK][AP];
    __shared__ float Ws[BK][BN];
    __shared__ float sredA[16][64];
    __shared__ float sredB[16][64];
    const int tid = threadIdx.x;
    const int tx = tid & 15;
    const int ty = tid >> 4;
    const int m0 = tx * 4, n0 = ty * 4;
    const int brow = blockIdx.x * BM;
    const int bcol = blockIdx.y * BN;
    const int sm = tid & 63;
    const int sk4 = tid >> 6;
    float acc[4][4] = {{0.f}};
    for (int k0 = 0; k0 < H; k0 += BK) {
#pragma unroll
        for (int half = 0; half < 2; ++half) {
            int kk = 4 * sk4 + 16 * half;
            float4 a = *reinterpret_cast<const float4*>(&hin[(brow + sm) * H + k0 + kk]);
            As[kk + 0][sm] = a.x;
            As[kk + 1][sm] = a.y;
            As[kk + 2][sm] = a.z;
            As[kk + 3][sm] = a.w;
        }
#pragma unroll
        for (int half = 0; half < 2; ++half) {
            int idx = tid + 256 * half;
            int kr = idx >> 4;
            int nq = idx & 15;
            float4 w = *reinterpret_cast<const float4*>(&W[(k0 + kr) * H + bcol + nq * 4]);
            *reinterpret_cast<float4*>(&Ws[kr][nq * 4]) = w;
        }
        __syncthreads();
#pragma unroll
        for (int k = 0; k < BK; ++k) {
            float4 av = *reinterpret_cast<const float4*>(&As[k][m0]);
            float4 wv = *reinterpret_cast<const float4*>(&Ws[k][n0]);
            float a[4] = {av.x, av.y, av.z, av.w};
            float w[4] = {wv.x, wv.y, wv.z, wv.w};
#pragma unroll
            for (int i = 0; i < 4; ++i)
#pragma unroll
                for (int j = 0; j < 4; ++j) acc[i][j] = fmaf(a[i], w[j], acc[i][j]);
        }
        __syncthreads();
    }
    float v[4][4];
    float4 wanv, wasv;
    if (!LAST) {
        wanv = *reinterpret_cast<const float4*>(&Watt[bcol + n0]);
        wasv = *reinterpret_cast<const float4*>(&Watt[H + bcol + n0]);
    }
#pragma unroll
    for (int i = 0; i < 4; ++i) {
#pragma unroll
        for (int j = 0; j < 4; ++j) {
            float x = acc[i][j] + b[bcol + n0 + j];
            v[i][j] = x > 0.f ? x : 0.f;
        }
        if (!LAST) {
            ushort4 o;
            o.x = f2bf(v[i][0]); o.y = f2bf(v[i][1]);
            o.z = f2bf(v[i][2]); o.w = f2bf(v[i][3]);
            *reinterpret_cast<ushort4*>(&hout[(brow + m0 + i) * H + bcol + n0]) = o;
        }
    }
    if (!LAST) {
#pragma unroll
        for (int i = 0; i < 4; ++i) {
            float pn = v[i][0]*wanv.x + v[i][1]*wanv.y + v[i][2]*wanv.z + v[i][3]*wanv.w;
            float ps = v[i][0]*wasv.x + v[i][1]*wasv.y + v[i][2]*wasv.z + v[i][3]*wasv.w;
            sredA[ty][m0 + i] = pn;
            sredB[ty][m0 + i] = ps;
        }
        __syncthreads();
        if (tid < 64) {
            float s = 0.f;
#pragma unroll
            for (int q = 0; q < 16; ++q) s += sredA[q][tid];
            atomicAdd(&snei_out[brow + tid], s);
        } else if (tid < 128) {
            int r = tid - 64;
            float s = 0.f;
#pragma unroll
            for (int q = 0; q < 16; ++q) s += sredB[q][r];
            atomicAdd(&sself_out[brow + r], s);
        }
    } else {
        float cp[4];
#pragma unroll
        for (int j = 0; j < 4; ++j) cp[j] = (v[0][j] + v[1][j]) + (v[2][j] + v[3][j]);
#pragma unroll
        for (int j = 0; j < 4; ++j) sredA[tx][n0 + j] = cp[j];
        __syncthreads();
        if (tid < 64) {
            float s = 0.f;
#pragma unroll
            for (int q = 0; q < 16; ++q) s += sredA[q][tid];
            part[blockIdx.x * 256 + bcol + tid] = s;
        }
    }
}

// ==== k_ro: whole readout, one 512-thread block, W in ORIGINAL [k][o] layout ====
__global__ __launch_bounds__(512) void k_ro(
    const float* __restrict__ part, const float* __restrict__ mol,
    const float* __restrict__ W1, const float* __restrict__ b1,
    const float* __restrict__ Wh, const float* __restrict__ bh,
    const float* __restrict__ Wo, const float* __restrict__ bo,
    float* __restrict__ out) {
    __shared__ float xa[512], xb[512], red[512];
    const int t = threadIdx.x;
    {
        const int col = t & 255;
        const int r0 = (t < 256) ? 0 : 64;
        float s = 0.f;
        for (int r = 0; r < 64; ++r) s += part[(r0 + r) * 256 + col];
        red[t] = s;
    }
    __syncthreads();
    if (t < 256) xa[t] = red[t] + red[t + 256];
    else { int i = t - 256; xa[256 + i] = (i < MF) ? mol[i] : 0.f; }
    __syncthreads();
    float* xin = xa;
    float* xo = xb;
#pragma unroll 1
    for (int L = 0; L < 3; ++L) {
        const float* Wl = (L == 0) ? W1 : (Wh + (L - 1) * RH * RH);
        const float* bl = (L == 0) ? b1 : (bh + (L - 1) * RH);
        const int K = (L == 0) ? (H + MF) : RH;
        float acc = 0.f;
        int k = 0;
#pragma unroll 8
        for (; k + 8 <= K; k += 8) {
#pragma unroll
            for (int u = 0; u < 8; ++u)
                acc = fmaf(xin[k + u], Wl[(k + u) * RH + t], acc);
        }
        for (; k < K; ++k) acc = fmaf(xin[k], Wl[k * RH + t], acc);
        float vv = acc + bl[t];
        xo[t] = vv > 0.f ? vv : 0.f;
        __syncthreads();
        float* tmp = xin; xin = xo; xo = tmp;
    }
    red[t] = xin[t] * Wo[t];
    __syncthreads();
    for (int s = 256; s > 0; s >>= 1) {
        if (t < s) red[t] += red[t + s];
        __syncthreads();
    }
    if (t == 0) out[0] = red[0] + bo[0];
}

extern "C" void kernel_launch(void* const* d_in, const int* in_sizes, int n_in,
                              void* d_out, int out_size, void* d_ws, size_t ws_size,
                              hipStream_t stream) {
    const float* A        = (const float*)d_in[0];
    const float* X        = (const float*)d_in[1];
    const float* mol      = (const float*)d_in[2];
    const float* W_in     = (const float*)d_in[3];
    const float* b_in     = (const float*)d_in[4];
    const float* W_att    = (const float*)d_in[5];
    const float* b_att    = (const float*)d_in[6];
    const float* W_node   = (const float*)d_in[7];
    const float* b_node   = (const float*)d_in[8];
    const float* W_ro_in  = (const float*)d_in[9];
    const float* b_ro_in  = (const float*)d_in[10];
    const float* W_ro_hid = (const float*)d_in[11];
    const float* b_ro_hid = (const float*)d_in[12];
    const float* W_out    = (const float*)d_in[13];
    const float* b_out    = (const float*)d_in[14];

    char* ws = (char*)d_ws;
    bfu*      hb     = (bfu*)     (ws);                   // 4 MB bf16 h
    float*    hg     = (float*)   (ws + 4194304);         // 8 MB fp32 aggregate
    int*      colidx = (int*)     (ws + 12582912);        // 4 MB
    unsigned* bmask  = (unsigned*)(ws + 16777216);        // 8 MB
    int*      cnt    = (int*)     (ws + 25165824);        // 32 KB
    float*    s0n    = (float*)   (ws + 25198592);        // 32 KB
    float*    s0s    = (float*)   (ws + 25231360);        // 32 KB
    float*    s1n    = (float*)   (ws + 25264128);        // 32 KB
    float*    s1s    = (float*)   (ws + 25296896);        // 32 KB
    float*    part   = (float*)   (ws + 25329664);        // 128 KB

    // front: h0+scores0 (blocks 0..255) | A->bitmask (256..2303)
    k_front<<<2304, 256, 0, stream>>>((const float4*)A, bmask,
                                      X, W_in, b_in, W_att, hb, s0n, s0s);
    k_extract<<<N / 4, 256, 0, stream>>>(bmask, cnt, colidx);
    // depth 0
    k_agg<<<N / 4, 256, 0, stream>>>(hb, hg, cnt, colidx, s0n, s0s, b_att, s1n, s1s);
    k_node<false><<<dim3(N / BM, H / BN), 256, 0, stream>>>(
        hg, hb, W_node + 0 * H * H, b_node + 0 * H, W_att, s1n, s1s, nullptr);
    // depth 1
    k_agg<<<N / 4, 256, 0, stream>>>(hb, hg, cnt, colidx, s1n, s1s, b_att, s0n, s0s);
    k_node<false><<<dim3(N / BM, H / BN), 256, 0, stream>>>(
        hg, hb, W_node + 1 * H * H, b_node + 1 * H, W_att, s0n, s0s, nullptr);
    // depth 2 (last): colsum partials, no h store
    k_agg<<<N / 4, 256, 0, stream>>>(hb, hg, cnt, colidx, s0n, s0s, b_att, s1n, s1s);
    k_node<true><<<dim3(N / BM, H / BN), 256, 0, stream>>>(
        hg, nullptr, W_node + 2 * H * H, b_node + 2 * H, W_att, nullptr, nullptr, part);
    // fused readout
    k_ro<<<1, 512, 0, stream>>>(part, mol, W_ro_in, b_ro_in, W_ro_hid, b_ro_hid,
                                W_out, b_out, (float*)d_out);
}

// Round 12
// 335.473 us; speedup vs baseline: 2.2850x; 2.2850x over previous
//
#include <hip/hip_runtime.h>
#include <hip/hip_bf16.h>
#include <math.h>

#define N 8192
#define F 133
#define FP 136
#define H 256
#define MF 200
#define RH 512
#define MAXDEG 128

typedef unsigned short bfu;

static __device__ __forceinline__ bfu f2bf(float f) {
    unsigned u = __builtin_bit_cast(unsigned, f);
    u = (u + 0x7fff + ((u >> 16) & 1)) >> 16;   // RNE, finite inputs
    return (bfu)u;
}
static __device__ __forceinline__ float bf2f(bfu b) {
    unsigned u = (unsigned)b << 16;
    return __builtin_bit_cast(float, u);
}

// ==== k_front: h0+scores0 (blocks 0..255) | A scan+extract (256..2303) ====
// Scan: branchless bitmask build in registers (8 independent 1KB loads/iter,
// cmp+select only), then in-register popcount/prefix/ffs extraction.
__global__ __launch_bounds__(256) void k_front(
    const float4* __restrict__ A4, int* __restrict__ cnt, int* __restrict__ colidx,
    const float* __restrict__ X, const float* __restrict__ Win,
    const float* __restrict__ bin, const float* __restrict__ Watt,
    bfu* __restrict__ hb, float* __restrict__ snei, float* __restrict__ sself) {
    const int t = threadIdx.x;
    const int b = blockIdx.x;
    if (b >= 256) {
        const int lane = t & 63;
        const int row = (b - 256) * 4 + (t >> 6);
        const float4* rowp = A4 + (size_t)row * (N / 4);
        unsigned w4[4];
#pragma unroll 1
        for (int c = 0; c < 4; ++c) {
            float4 v[8];
#pragma unroll
            for (int j = 0; j < 8; ++j) v[j] = rowp[c * 512 + j * 64 + lane];
            unsigned m = 0;
#pragma unroll
            for (int j = 0; j < 8; ++j) {
                const float* vp = &v[j].x;
#pragma unroll
                for (int q = 0; q < 4; ++q)
                    m |= (vp[q] != 0.0f) ? (1u << (j * 4 + q)) : 0u;
            }
            w4[c] = m;
        }
        // in-register extraction (mapping verified in R11's k_extract)
        int tl = __popc(w4[0]) + __popc(w4[1]) + __popc(w4[2]) + __popc(w4[3]);
        int inc = tl;
#pragma unroll
        for (int d = 1; d < 64; d <<= 1) {
            int nb = __shfl_up(inc, d);
            if (lane >= d) inc += nb;
        }
        int o = inc - tl;
        if (lane == 63) cnt[row] = inc < MAXDEG ? inc : MAXDEG;
        int* rowout = colidx + row * MAXDEG;
#pragma unroll
        for (int c = 0; c < 4; ++c) {
            unsigned m = w4[c];
            const int base = c * 2048 + lane * 4;
            while (m) {
                int p = __ffs(m) - 1;
                m &= m - 1;
                if (o < MAXDEG) rowout[o] = base + ((p >> 2) << 8) + (p & 3);
                ++o;
            }
        }
        return;
    }
    // ---------------- h0 = X @ W_in + b_in -> bf16, + scores of h0 ----------------
    __shared__ float xs[32][FP];
    __shared__ float sredN[32][4];
    __shared__ float sredS[32][4];
    const int row0 = b * 32;
    for (int i = t; i < 32 * F; i += 256) {
        int r = i / F, f = i - r * F;
        xs[r][f] = X[(row0 + r) * F + f];
    }
    __syncthreads();
    float acc[32];
#pragma unroll
    for (int r = 0; r < 32; ++r) acc[r] = 0.f;
    for (int f = 0; f < 132; f += 4) {
        float w0 = Win[(f + 0) * H + t];
        float w1 = Win[(f + 1) * H + t];
        float w2 = Win[(f + 2) * H + t];
        float w3 = Win[(f + 3) * H + t];
#pragma unroll
        for (int r = 0; r < 32; ++r) {
            float4 xv = *reinterpret_cast<const float4*>(&xs[r][f]);
            acc[r] = fmaf(xv.x, w0, acc[r]);
            acc[r] = fmaf(xv.y, w1, acc[r]);
            acc[r] = fmaf(xv.z, w2, acc[r]);
            acc[r] = fmaf(xv.w, w3, acc[r]);
        }
    }
    {
        float w0 = Win[132 * H + t];
#pragma unroll
        for (int r = 0; r < 32; ++r) acc[r] = fmaf(xs[r][132], w0, acc[r]);
    }
    const float bb = bin[t];
    const float wan = Watt[t];
    const float was = Watt[H + t];
    const int wv = t >> 6, ln = t & 63;
#pragma unroll
    for (int r = 0; r < 32; ++r) {
        float v = acc[r] + bb;
        hb[(row0 + r) * H + t] = f2bf(v);
        float pn = v * wan;
        float ps = v * was;
        for (int off = 32; off > 0; off >>= 1) {
            pn += __shfl_down(pn, off);
            ps += __shfl_down(ps, off);
        }
        if (ln == 0) { sredN[r][wv] = pn; sredS[r][wv] = ps; }
    }
    __syncthreads();
    if (t < 32)
        snei[row0 + t] = (sredN[t][0] + sredN[t][1]) + (sredN[t][2] + sredN[t][3]);
    else if (t < 64) {
        int r = t - 32;
        sself[row0 + r] = (sredS[r][0] + sredS[r][1]) + (sredS[r][2] + sredS[r][3]);
    }
}

// ============ k_agg: gather h (bf16) -> hg (fp32); zero next score bufs ============
__global__ __launch_bounds__(256, 4) void k_agg(
    const bfu* __restrict__ hb, float* __restrict__ hg,
    const int* __restrict__ cnt, const int* __restrict__ colidx,
    const float* __restrict__ snei_in, const float* __restrict__ sself_in,
    const float* __restrict__ b_att,
    float* __restrict__ zn, float* __restrict__ zs) {
    __shared__ float wls[512];
    __shared__ int   jls[512];
    __shared__ float sselfL[4];
    __shared__ int   ncnt[4];
    const int t = threadIdx.x;
    const int w = t >> 6, l = t & 63;
    const int c0 = l << 2;
    const int R0 = blockIdx.x * 4;
    if (blockIdx.x < 64) {   // zero the score buffers the next k_node atomic-adds
        if (t < 128) zn[blockIdx.x * 128 + t] = 0.f;
        else         zs[blockIdx.x * 128 + (t - 128)] = 0.f;
    }
    if (t < 4) { ncnt[t] = cnt[R0 + t]; sselfL[t] = sself_in[R0 + t] + b_att[0]; }
    __syncthreads();
#pragma unroll
    for (int rep = 0; rep < 2; ++rep) {
        int idx = t + rep * 256;
        int r = idx >> 7, k = idx & 127;
        if (k < ncnt[r]) {
            int j = colidx[(R0 + r) * MAXDEG + k];
            jls[idx] = j;
            wls[idx] = 1.f / (1.f + __expf(-(sselfL[r] + snei_in[j])));
        }
    }
    __syncthreads();
    const int n = ncnt[w];
#define GSTEP(u, sx, sy, sz, sw)                                                  \
    { int ju = jls[w * 128 + k + u]; float wv = wls[w * 128 + k + u];             \
      ushort4 hv = *reinterpret_cast<const ushort4*>(&hb[ju * 256 + c0]);         \
      sx = fmaf(wv, bf2f(hv.x), sx); sy = fmaf(wv, bf2f(hv.y), sy);               \
      sz = fmaf(wv, bf2f(hv.z), sz); sw = fmaf(wv, bf2f(hv.w), sw); }
    float x0=0,y0=0,z0=0,w0=0, x1=0,y1=0,z1=0,w1=0;
    float x2=0,y2=0,z2=0,w2=0, x3=0,y3=0,z3=0,w3=0;
    float x4=0,y4=0,z4=0,w4=0, x5=0,y5=0,z5=0,w5=0;
    float x6=0,y6=0,z6=0,w6=0, x7=0,y7=0,z7=0,w7=0;
    int k = 0;
    for (; k + 8 <= n; k += 8) {
        GSTEP(0,x0,y0,z0,w0) GSTEP(1,x1,y1,z1,w1)
        GSTEP(2,x2,y2,z2,w2) GSTEP(3,x3,y3,z3,w3)
        GSTEP(4,x4,y4,z4,w4) GSTEP(5,x5,y5,z5,w5)
        GSTEP(6,x6,y6,z6,w6) GSTEP(7,x7,y7,z7,w7)
    }
    for (; k < n; ++k) { GSTEP(0,x0,y0,z0,w0) }
#undef GSTEP
    float4 st;
    st.x = ((x0+x1)+(x2+x3)) + ((x4+x5)+(x6+x7));
    st.y = ((y0+y1)+(y2+y3)) + ((y4+y5)+(y6+y7));
    st.z = ((z0+z1)+(z2+z3)) + ((z4+z5)+(z6+z7));
    st.w = ((w0+w1)+(w2+w3)) + ((w4+w5)+(w6+w7));
    *reinterpret_cast<float4*>(&hg[(size_t)(R0 + w) * 256 + c0]) = st;
}

// ===== k_node: h_next = relu(hg @ W + b); epilogue: atomic scores | colsum part =====
#define BM 64
#define BN 64
#define BK 32
#define AP 68
template <bool LAST>
__global__ __launch_bounds__(256) void k_node(
    const float* __restrict__ hin, bfu* __restrict__ hout,
    const float* __restrict__ W, const float* __restrict__ b,
    const float* __restrict__ Watt,
    float* __restrict__ snei_out, float* __restrict__ sself_out,
    float* __restrict__ part) {
    __shared__ float As[BK][AP];
    __shared__ float Ws[BK][BN];
    __shared__ float sredA[16][64];
    __shared__ float sredB[16][64];
    const int tid = threadIdx.x;
    const int tx = tid & 15;
    const int ty = tid >> 4;
    const int m0 = tx * 4, n0 = ty * 4;
    const int brow = blockIdx.x * BM;
    const int bcol = blockIdx.y * BN;
    const int sm = tid & 63;
    const int sk4 = tid >> 6;
    float acc[4][4] = {{0.f}};
    for (int k0 = 0; k0 < H; k0 += BK) {
#pragma unroll
        for (int half = 0; half < 2; ++half) {
            int kk = 4 * sk4 + 16 * half;
            float4 a = *reinterpret_cast<const float4*>(&hin[(brow + sm) * H + k0 + kk]);
            As[kk + 0][sm] = a.x;
            As[kk + 1][sm] = a.y;
            As[kk + 2][sm] = a.z;
            As[kk + 3][sm] = a.w;
        }
#pragma unroll
        for (int half = 0; half < 2; ++half) {
            int idx = tid + 256 * half;
            int kr = idx >> 4;
            int nq = idx & 15;
            float4 w = *reinterpret_cast<const float4*>(&W[(k0 + kr) * H + bcol + nq * 4]);
            *reinterpret_cast<float4*>(&Ws[kr][nq * 4]) = w;
        }
        __syncthreads();
#pragma unroll
        for (int k = 0; k < BK; ++k) {
            float4 av = *reinterpret_cast<const float4*>(&As[k][m0]);
            float4 wv = *reinterpret_cast<const float4*>(&Ws[k][n0]);
            float a[4] = {av.x, av.y, av.z, av.w};
            float w[4] = {wv.x, wv.y, wv.z, wv.w};
#pragma unroll
            for (int i = 0; i < 4; ++i)
#pragma unroll
                for (int j = 0; j < 4; ++j) acc[i][j] = fmaf(a[i], w[j], acc[i][j]);
        }
        __syncthreads();
    }
    float v[4][4];
    float4 wanv, wasv;
    if (!LAST) {
        wanv = *reinterpret_cast<const float4*>(&Watt[bcol + n0]);
        wasv = *reinterpret_cast<const float4*>(&Watt[H + bcol + n0]);
    }
#pragma unroll
    for (int i = 0; i < 4; ++i) {
#pragma unroll
        for (int j = 0; j < 4; ++j) {
            float x = acc[i][j] + b[bcol + n0 + j];
            v[i][j] = x > 0.f ? x : 0.f;
        }
        if (!LAST) {
            ushort4 o;
            o.x = f2bf(v[i][0]); o.y = f2bf(v[i][1]);
            o.z = f2bf(v[i][2]); o.w = f2bf(v[i][3]);
            *reinterpret_cast<ushort4*>(&hout[(brow + m0 + i) * H + bcol + n0]) = o;
        }
    }
    if (!LAST) {
#pragma unroll
        for (int i = 0; i < 4; ++i) {
            float pn = v[i][0]*wanv.x + v[i][1]*wanv.y + v[i][2]*wanv.z + v[i][3]*wanv.w;
            float ps = v[i][0]*wasv.x + v[i][1]*wasv.y + v[i][2]*wasv.z + v[i][3]*wasv.w;
            sredA[ty][m0 + i] = pn;
            sredB[ty][m0 + i] = ps;
        }
        __syncthreads();
        if (tid < 64) {
            float s = 0.f;
#pragma unroll
            for (int q = 0; q < 16; ++q) s += sredA[q][tid];
            atomicAdd(&snei_out[brow + tid], s);
        } else if (tid < 128) {
            int r = tid - 64;
            float s = 0.f;
#pragma unroll
            for (int q = 0; q < 16; ++q) s += sredB[q][r];
            atomicAdd(&sself_out[brow + r], s);
        }
    } else {
        float cp[4];
#pragma unroll
        for (int j = 0; j < 4; ++j) cp[j] = (v[0][j] + v[1][j]) + (v[2][j] + v[3][j]);
#pragma unroll
        for (int j = 0; j < 4; ++j) sredA[tx][n0 + j] = cp[j];
        __syncthreads();
        if (tid < 64) {
            float s = 0.f;
#pragma unroll
            for (int q = 0; q < 16; ++q) s += sredA[q][tid];
            part[blockIdx.x * 256 + bcol + tid] = s;
        }
    }
}

// ==== readout tail: 8-block K-split kernels (proven R3 structure) ====
__global__ __launch_bounds__(256) void k_ro1(const float* __restrict__ part,
                                             const float* __restrict__ mol,
                                             const float* __restrict__ W,
                                             const float* __restrict__ b,
                                             const float* __restrict__ bo,
                                             float* __restrict__ g1,
                                             float* __restrict__ outsc) {
    __shared__ float xin[H + MF];
    __shared__ float red[256];
    const int t = threadIdx.x;
    {
        float s0 = 0.f, s1 = 0.f, s2 = 0.f, s3 = 0.f;
        for (int r = 0; r < 128; r += 4) {
            s0 += part[(r + 0) * H + t];
            s1 += part[(r + 1) * H + t];
            s2 += part[(r + 2) * H + t];
            s3 += part[(r + 3) * H + t];
        }
        xin[t] = (s0 + s1) + (s2 + s3);
    }
    if (t < MF) xin[H + t] = mol[t];
    if (blockIdx.x == 0 && t == 0) outsc[0] = bo[0];   // init for later atomics
    __syncthreads();
    const int o = blockIdx.x * 64 + (t & 63);
    const int kg = t >> 6;
    float acc = 0.f;
    for (int k = kg; k < H + MF; k += 4) acc = fmaf(xin[k], W[k * RH + o], acc);
    red[t] = acc;
    __syncthreads();
    if (t < 64) {
        float v = red[t] + red[t + 64] + red[t + 128] + red[t + 192] + b[o];
        g1[o] = v > 0.f ? v : 0.f;
    }
}

__global__ __launch_bounds__(256) void k_ro_hid(const float* __restrict__ g,
                                                const float* __restrict__ W,
                                                const float* __restrict__ b,
                                                float* __restrict__ out) {
    __shared__ float xin[RH];
    __shared__ float red[256];
    const int t = threadIdx.x;
    xin[t] = g[t];
    xin[t + 256] = g[t + 256];
    __syncthreads();
    const int o = blockIdx.x * 64 + (t & 63);
    const int kg = t >> 6;
    float acc = 0.f;
    for (int k = kg; k < RH; k += 4) acc = fmaf(xin[k], W[k * RH + o], acc);
    red[t] = acc;
    __syncthreads();
    if (t < 64) {
        float v = red[t] + red[t + 64] + red[t + 128] + red[t + 192] + b[o];
        out[o] = v > 0.f ? v : 0.f;
    }
}

// layer 3 + fused dot: per-block 64-output slice, wave-reduce, one atomicAdd
__global__ __launch_bounds__(256) void k_ro_hid_dot(const float* __restrict__ g,
                                                    const float* __restrict__ W,
                                                    const float* __restrict__ b,
                                                    const float* __restrict__ Wo,
                                                    float* __restrict__ outsc) {
    __shared__ float xin[RH];
    __shared__ float red[256];
    const int t = threadIdx.x;
    xin[t] = g[t];
    xin[t + 256] = g[t + 256];
    __syncthreads();
    const int o = blockIdx.x * 64 + (t & 63);
    const int kg = t >> 6;
    float acc = 0.f;
    for (int k = kg; k < RH; k += 4) acc = fmaf(xin[k], W[k * RH + o], acc);
    red[t] = acc;
    __syncthreads();
    if (t < 64) {
        float v = red[t] + red[t + 64] + red[t + 128] + red[t + 192] + b[o];
        v = v > 0.f ? v : 0.f;
        float p = v * Wo[o];
#pragma unroll
        for (int off = 32; off > 0; off >>= 1) p += __shfl_down(p, off);
        if (t == 0) atomicAdd(outsc, p);
    }
}

extern "C" void kernel_launch(void* const* d_in, const int* in_sizes, int n_in,
                              void* d_out, int out_size, void* d_ws, size_t ws_size,
                              hipStream_t stream) {
    const float* A        = (const float*)d_in[0];
    const float* X        = (const float*)d_in[1];
    const float* mol      = (const float*)d_in[2];
    const float* W_in     = (const float*)d_in[3];
    const float* b_in     = (const float*)d_in[4];
    const float* W_att    = (const float*)d_in[5];
    const float* b_att    = (const float*)d_in[6];
    const float* W_node   = (const float*)d_in[7];
    const float* b_node   = (const float*)d_in[8];
    const float* W_ro_in  = (const float*)d_in[9];
    const float* b_ro_in  = (const float*)d_in[10];
    const float* W_ro_hid = (const float*)d_in[11];
    const float* b_ro_hid = (const float*)d_in[12];
    const float* W_out    = (const float*)d_in[13];
    const float* b_out    = (const float*)d_in[14];

    char* ws = (char*)d_ws;
    bfu*   hb     = (bfu*)  (ws);                        // 4 MB bf16 h
    float* hg     = (float*)(ws + 4194304);              // 8 MB fp32 aggregate
    int*   colidx = (int*)  (ws + 12582912);             // 4 MB
    int*   cnt    = (int*)  (ws + 16777216);             // 32 KB
    float* s0n    = (float*)(ws + 16809984);             // 32 KB
    float* s0s    = (float*)(ws + 16842752);             // 32 KB
    float* s1n    = (float*)(ws + 16875520);             // 32 KB
    float* s1s    = (float*)(ws + 16908288);             // 32 KB
    float* part   = (float*)(ws + 16941056);             // 128 KB
    float* g1     = (float*)(ws + 17072128);             // 2 KB
    float* g2     = (float*)(ws + 17074176);             // 2 KB

    // front: h0+scores0 (blocks 0..255) | A scan+extract (256..2303)
    k_front<<<2304, 256, 0, stream>>>((const float4*)A, cnt, colidx,
                                      X, W_in, b_in, W_att, hb, s0n, s0s);
    // depth 0
    k_agg<<<N / 4, 256, 0, stream>>>(hb, hg, cnt, colidx, s0n, s0s, b_att, s1n, s1s);
    k_node<false><<<dim3(N / BM, H / BN), 256, 0, stream>>>(
        hg, hb, W_node + 0 * H * H, b_node + 0 * H, W_att, s1n, s1s, nullptr);
    // depth 1
    k_agg<<<N / 4, 256, 0, stream>>>(hb, hg, cnt, colidx, s1n, s1s, b_att, s0n, s0s);
    k_node<false><<<dim3(N / BM, H / BN), 256, 0, stream>>>(
        hg, hb, W_node + 1 * H * H, b_node + 1 * H, W_att, s0n, s0s, nullptr);
    // depth 2 (last): colsum partials, no h store
    k_agg<<<N / 4, 256, 0, stream>>>(hb, hg, cnt, colidx, s0n, s0s, b_att, s1n, s1s);
    k_node<true><<<dim3(N / BM, H / BN), 256, 0, stream>>>(
        hg, nullptr, W_node + 2 * H * H, b_node + 2 * H, W_att, nullptr, nullptr, part);
    // readout tail (8-block K-split kernels; fp32 exact)
    k_ro1<<<RH / 64, 256, 0, stream>>>(part, mol, W_ro_in, b_ro_in, b_out, g1,
                                       (float*)d_out);
    k_ro_hid<<<RH / 64, 256, 0, stream>>>(g1, W_ro_hid, b_ro_hid, g2);
    k_ro_hid_dot<<<RH / 64, 256, 0, stream>>>(g2, W_ro_hid + RH * RH, b_ro_hid + RH,
                                              W_out, (float*)d_out);
}